// Round 3
// baseline (899.305 us; speedup 1.0000x reference)
//
#include <hip/hip_runtime.h>
#include <math.h>

#define Bsz 32
#define Nn 207
#define Tt 12
#define Cc 2
#define HORr 12
#define DIDd 64
#define Hh 128
#define NBb 3
#define CONCATk 2560
#define BN (Bsz*Nn)           // 6624
#define ROWS (BN*Cc)          // 13248 = 414*32
#define XSTRIDE (CONCATk*Cc)  // 5120

typedef unsigned short u16;
typedef __attribute__((ext_vector_type(8))) short bf16x8;
typedef __attribute__((ext_vector_type(4))) float f32x4;

__device__ inline u16 f2b(float f) {
  unsigned u = __builtin_bit_cast(unsigned, f);
  u += 0x7fffu + ((u >> 16) & 1u);          // RNE
  return (u16)(u >> 16);
}
__device__ inline float b2f(u16 b) {
  unsigned u = ((unsigned)b) << 16;
  return __builtin_bit_cast(float, u);
}

// ---------------- K1: time gates + h_in + level + zero f_acc ----------------
__global__ __launch_bounds__(128) void k_timegate(
    const float* __restrict__ hist, const float* __restrict__ tod,
    const float* __restrict__ emb,
    const float* __restrict__ w1, const float* __restrict__ b1,
    const float* __restrict__ w2, const float* __restrict__ b2,
    const float* __restrict__ w3, const float* __restrict__ b3,
    float* __restrict__ h_in, float* __restrict__ level,
    float* __restrict__ tgf, float* __restrict__ f_acc)
{
  int bn = blockIdx.x;
  int n = bn % Nn;
  __shared__ float s_in[76];
  __shared__ float s_tg[128];
  __shared__ float s_tgb[12];
  __shared__ float s_h[24];
  int tid = threadIdx.x;
  if (tid < 64) s_in[tid] = emb[n*64 + tid];
  else if (tid < 76) s_in[tid] = tod[bn*12 + (tid - 64)];
  __syncthreads();
  float acc = b1[tid];
#pragma unroll 4
  for (int k = 0; k < 76; ++k) acc = fmaf(s_in[k], w1[k*128 + tid], acc);
  s_tg[tid] = fmaxf(acc, 0.f);
  __syncthreads();
  if (tid < 24) {
    int j = tid % 12;
    const float* w = (tid < 12) ? w2 : w3;
    float a = (tid < 12) ? b2[j] : b3[j];
    for (int k = 0; k < 128; ++k) a = fmaf(s_tg[k], w[k*12 + j], a);
    if (tid < 12) tgf[bn*12 + j] = a;
    else s_tgb[j] = a;
  }
  __syncthreads();
  if (tid < 24) {
    int t = tid >> 1;
    float v = hist[bn*24 + tid] / (1.f + s_tgb[t]);
    h_in[bn*24 + tid] = v;
    s_h[tid] = v;
    f_acc[bn*24 + tid] = 0.f;
  }
  __syncthreads();
  if (tid < 2) {
    float m = s_h[tid];
    for (int t = 1; t < 12; ++t) m = fmaxf(m, s_h[t*2 + tid]);
    level[bn*2 + tid] = m;
  }
}

// ---------------- K2: dp[n,m] = exp(10 * <emb_n, emb_m>) ----------------
__global__ __launch_bounds__(256) void k_dp(const float* __restrict__ emb,
                                            float* __restrict__ dp)
{
  int n = blockIdx.x;
  __shared__ float e[64];
  int tid = threadIdx.x;
  if (tid < 64) e[tid] = emb[n*64 + tid];
  __syncthreads();
  if (tid < Nn) {
    float a = 0.f;
#pragma unroll 8
    for (int k = 0; k < 64; ++k) a = fmaf(e[k], emb[tid*64 + k], a);
    dp[n*Nn + tid] = expf(10.f * a);
  }
}

// ---------------- weight transpose+convert: fp32 [K][N] -> bf16 [N][K] -------
__global__ __launch_bounds__(256) void k_transp(
    const float* __restrict__ src, u16* __restrict__ dst, int K, int N)
{
  int k0 = blockIdx.x*64, n0 = blockIdx.y*64;
  size_t mo = (size_t)blockIdx.z * K * N;
  src += mo; dst += mo;
  __shared__ u16 Ts[64][72];
  int tid = threadIdx.x;
#pragma unroll
  for (int it = 0; it < 4; ++it) {
    int idx = it*256 + tid;
    int r = idx >> 4, q = idx & 15;
    float4 v = *(const float4*)(src + (size_t)(k0 + r)*N + n0 + q*4);
    Ts[r][q*4+0] = f2b(v.x);
    Ts[r][q*4+1] = f2b(v.y);
    Ts[r][q*4+2] = f2b(v.z);
    Ts[r][q*4+3] = f2b(v.w);
  }
  __syncthreads();
#pragma unroll
  for (int it = 0; it < 2; ++it) {
    int idx = it*256 + tid;
    int nl = idx >> 3, kq = idx & 7;
    u16 o[8];
#pragma unroll
    for (int j = 0; j < 8; ++j) o[j] = Ts[kq*8 + j][nl];
    *(bf16x8*)(dst + (size_t)(n0 + nl)*K + k0 + kq*8) = *(bf16x8*)o;
  }
}

// ---------------- build xb bf16, row-major [r=bn*2+c][k] ---------------------
__global__ __launch_bounds__(256) void k_build_b(
    const float* __restrict__ h_in, const float* __restrict__ level,
    const float* __restrict__ dp, const float* __restrict__ emb,
    u16* __restrict__ xb)
{
  int bn = blockIdx.x;
  int b = bn / Nn, n = bn - b*Nn;
  __shared__ float s_dp[Nn];
  int tid = threadIdx.x;
  for (int m = tid; m < Nn; m += 256) s_dp[m] = dp[n*Nn + m];
  __syncthreads();
  float lev[2] = {level[bn*2], level[bn*2+1]};
  float inv[2] = {1.f/(lev[0]+1e-8f), 1.f/(lev[1]+1e-8f)};
  const float* hb = h_in + (size_t)b*Nn*24;
  for (int s = tid; s < 640; s += 256) {
    int c = s / 320, ks = s - c*320;
    u16 o[8];
#pragma unroll
    for (int j = 0; j < 8; ++j) {
      int k = ks*8 + j;
      float v;
      if (k < 12) v = h_in[bn*24 + k*2 + c] * inv[c];
      else if (k < 2496) {
        int q = k - 12; int m = q / 12, t = q - m*12;
        v = fmaxf((hb[m*24 + t*2 + c]*s_dp[m] - lev[c]) * inv[c], 0.f);
      } else v = emb[n*64 + (k - 2496)];
      o[j] = f2b(v);
    }
    *(bf16x8*)(xb + (size_t)(bn*2 + c)*2560 + ks*8) = *(bf16x8*)o;
  }
}

// ---------------- fused N-BEATS block: fc0->h1->h2->h3 + fore + back ---------
// Round-3: NO global_load_lds, NO LDS weight staging. Rounds 0-2 showed k_mega
// time tracks bytes staged through the LDS-DMA path (~25 GB/s/CU) regardless
// of schedule; the weight panels (1.28 MB/block, L2-resident, shared by all
// blocks) were the staged bulk. Now A and B fragments are loaded straight
// global->VGPR (naturally 16B-aligned bf16x8 chunks) and fed to MFMA from
// registers; L1 absorbs intra-block fragment re-reads, L2 serves the shared
// weight panels. LDS holds only the 8 KB h-tile for cross-wave exchange.
// 512 threads = 8 waves (2 row-halves x 4 col-groups), 6 __syncthreads total,
// no other synchronization.
template<int FINAL>
__global__ __launch_bounds__(512, 4) void k_mega(
    u16* __restrict__ xb,
    const u16* __restrict__ W0t, const float* __restrict__ b0,
    const u16* __restrict__ W1t, const float* __restrict__ b1,
    const u16* __restrict__ W2t, const float* __restrict__ b2,
    const float* __restrict__ FW, const float* __restrict__ fb,
    const u16* __restrict__ BWt, const float* __restrict__ bbias,
    float* __restrict__ f_acc, float* __restrict__ xf)
{
  __shared__ __attribute__((aligned(16))) u16 Hs[32*16*8];  // 8 KB: h tile, XOR-swizzled
  const int tid = threadIdx.x, wv = tid >> 6, lane = tid & 63;
  const int m16 = lane & 15, quad = lane >> 4;
  const int wr  = (wv & 1) * 16;        // row half within the 32-row block
  const int wcg = wv >> 1;              // 0..3 col group
  const int wc  = wcg * 32;             // fc0/h col base (of 128)
  const int r0  = blockIdx.x * 32;

  // ---- fc0: acc[16x32 per wave] = xb[rows][2560] . W0t[cols][2560]^T ----
  const u16* ap  = xb  + (size_t)(r0 + wr + m16)*2560 + quad*8;
  const u16* bp0 = W0t + (size_t)(wc      + m16)*2560 + quad*8;
  const u16* bp1 = W0t + (size_t)(wc + 16 + m16)*2560 + quad*8;

  f32x4 acc0 = {}, acc1 = {};
#pragma unroll 4
  for (int k = 0; k < 2560; k += 32) {
    bf16x8 a  = *(const bf16x8*)(ap  + k);
    bf16x8 bv0 = *(const bf16x8*)(bp0 + k);
    bf16x8 bv1 = *(const bf16x8*)(bp1 + k);
    acc0 = __builtin_amdgcn_mfma_f32_16x16x32_bf16(a, bv0, acc0, 0, 0, 0);
    acc1 = __builtin_amdgcn_mfma_f32_16x16x32_bf16(a, bv1, acc1, 0, 0, 0);
  }

  // h writeback: relu(acc + bias) -> Hs, chunk-XOR swizzle vs bank conflicts
  auto writeH = [&](const f32x4& a0, const f32x4& a1, const float* bias) {
#pragma unroll
    for (int jj = 0; jj < 2; ++jj) {
      f32x4 av = jj ? a1 : a0;
      int col = wc + jj*16 + m16;
      float bv = bias[col];
#pragma unroll
      for (int reg = 0; reg < 4; ++reg) {
        int row = wr + quad*4 + reg;
        int chunk = col >> 3;
        Hs[(row*16 + (chunk ^ (row & 15)))*8 + (col & 7)] =
            f2b(fmaxf(av[reg] + bv, 0.f));
      }
    }
  };
  // h x W (K=128): A from Hs, B streamed from global (L2-hot)
  auto mm128 = [&](const u16* Wt, f32x4& o0, f32x4& o1) {
    const u16* q0 = Wt + (size_t)(wc      + m16)*128 + quad*8;
    const u16* q1 = Wt + (size_t)(wc + 16 + m16)*128 + quad*8;
#pragma unroll
    for (int ks = 0; ks < 4; ++ks) {
      int cb = ks*4 + quad;
      bf16x8 a = *(const bf16x8*)&Hs[((wr + m16)*16 + (cb ^ m16))*8];
      bf16x8 bv0 = *(const bf16x8*)(q0 + ks*32);
      bf16x8 bv1 = *(const bf16x8*)(q1 + ks*32);
      o0 = __builtin_amdgcn_mfma_f32_16x16x32_bf16(a, bv0, o0, 0, 0, 0);
      o1 = __builtin_amdgcn_mfma_f32_16x16x32_bf16(a, bv1, o1, 0, 0, 0);
    }
  };

  writeH(acc0, acc1, b0);          // h1 -> Hs
  __syncthreads();
  f32x4 c20 = {}, c21 = {};
  mm128(W1t, c20, c21);
  __syncthreads();
  writeH(c20, c21, b1);            // h2 -> Hs
  __syncthreads();
  f32x4 c30 = {}, c31 = {};
  mm128(W2t, c30, c31);
  __syncthreads();
  writeH(c30, c31, b2);            // h3 -> Hs (stays for fore + back)
  __syncthreads();

  // ---- forecast accumulation (waves 0-5; no barrier needed after) ----
  if (tid < 384) {
    int row = tid / 12, t = tid - (tid/12)*12;
    float a = fb[t];
#pragma unroll
    for (int chunk = 0; chunk < 16; ++chunk) {
      const u16* hp = &Hs[(row*16 + (chunk ^ (row & 15)))*8];
#pragma unroll
      for (int j = 0; j < 8; ++j)
        a = fmaf(b2f(hp[j]), FW[(chunk*8 + j)*12 + t], a);
    }
    f_acc[(size_t)(r0 + row)*12 + t] += a;
  }

  // ---- back: per wave 16 rows x 640 cols in 10 tiles of 64; no barriers ----
  const int c0 = wcg * 640;
  for (int t = 0; t < 10; ++t) {
    const int n0 = c0 + t*64;
    f32x4 bacc[4] = {};
    const u16* bq[4]; float bb[4];
#pragma unroll
    for (int jj = 0; jj < 4; ++jj) {
      bq[jj] = BWt + (size_t)(n0 + jj*16 + m16)*128 + quad*8;
      bb[jj] = bbias[n0 + jj*16 + m16];
    }
#pragma unroll
    for (int ks = 0; ks < 4; ++ks) {
      int cb = ks*4 + quad;
      bf16x8 a = *(const bf16x8*)&Hs[((wr + m16)*16 + (cb ^ m16))*8];
#pragma unroll
      for (int jj = 0; jj < 4; ++jj) {
        bf16x8 bv = *(const bf16x8*)(bq[jj] + ks*32);
        bacc[jj] = __builtin_amdgcn_mfma_f32_16x16x32_bf16(a, bv, bacc[jj], 0, 0, 0);
      }
    }
#pragma unroll
    for (int jj = 0; jj < 4; ++jj) {
      int col = n0 + jj*16 + m16;
      if constexpr (!FINAL) {
#pragma unroll
        for (int reg = 0; reg < 4; ++reg) {
          int row = r0 + wr + quad*4 + reg;
          u16* xp = xb + (size_t)row*2560 + col;
          *xp = f2b(fmaxf(b2f(*xp) - (bacc[jj][reg] + bb[jj]), 0.f));
        }
      } else {
#pragma unroll
        for (int pr = 0; pr < 2; ++pr) {
          int row = r0 + wr + quad*4 + pr*2;   // even; (row,row+1) = same bn, c=0/1
          const u16* x0 = xb + (size_t)row*2560 + col;
          const u16* x1 = xb + (size_t)(row+1)*2560 + col;
          float2 ov;
          ov.x = fmaxf(b2f(*x0) - (bacc[jj][pr*2+0] + bb[jj]), 0.f);
          ov.y = fmaxf(b2f(*x1) - (bacc[jj][pr*2+1] + bb[jj]), 0.f);
          *(float2*)(xf + (size_t)(row>>1)*XSTRIDE + (size_t)col*2) = ov;
        }
      }
    }
  }
}

// ---------------- finalize forecast ----------------
__global__ __launch_bounds__(256) void k_forecast(
    const float* __restrict__ f_acc, const float* __restrict__ level,
    const float* __restrict__ tgf, float* __restrict__ outf)
{
  int idx = blockIdx.x*256 + threadIdx.x;
  if (idx >= BN*24) return;
  int bn = idx / 24;
  int rem = idx - bn*24;
  int t = rem >> 1, c = rem & 1;
  float v = f_acc[bn*24 + c*12 + t];
  outf[idx] = v * level[bn*2 + c] * (1.f + tgf[bn*12 + t]);
}

extern "C" void kernel_launch(void* const* d_in, const int* in_sizes, int n_in,
                              void* d_out, int out_size, void* d_ws, size_t ws_size,
                              hipStream_t stream)
{
  const float* hist = (const float*)d_in[0];
  const float* tod  = (const float*)d_in[1];
  const float* emb  = (const float*)d_in[2];
  const float* tg1w = (const float*)d_in[3];
  const float* tg1b = (const float*)d_in[4];
  const float* tg2w = (const float*)d_in[5];
  const float* tg2b = (const float*)d_in[6];
  const float* tg3w = (const float*)d_in[7];
  const float* tg3b = (const float*)d_in[8];
  const float* fc0w = (const float*)d_in[9];
  const float* fc0b = (const float*)d_in[10];
  const float* fcw  = (const float*)d_in[11];
  const float* fcb  = (const float*)d_in[12];
  const float* forew= (const float*)d_in[13];
  const float* foreb= (const float*)d_in[14];
  const float* backw= (const float*)d_in[15];
  const float* backb= (const float*)d_in[16];

  char* w = (char*)d_ws;
  float* h_in  = (float*)w; w += 635904;     // 158976 f32
  float* level = (float*)w; w += 52992;      // 13248 f32
  float* tgf   = (float*)w; w += 317952;     // 79488 f32
  float* dp    = (float*)w; w += 171408;     // 42852 f32
  float* f_acc = (float*)w; w += 635904;     // 158976 f32
  u16* fc0wt   = (u16*)w;   w += 1966080;    // 3 x [128][2560]
  u16* fcwt    = (u16*)w;   w += 196608;     // 6 x [128][128]
  u16* backwt  = (u16*)w;   w += 1966080;    // 3 x [2560][128]
  u16* xb      = (u16*)w;   w += 67829760;   // 13248*2560 bf16

  float* x    = (float*)d_out;                               // [bn][k][c] fp32
  float* outf = (float*)d_out + (size_t)BN*CONCATk*Cc;

  k_transp<<<dim3(40, 2, 3), 256, 0, stream>>>(fc0w, fc0wt, 2560, 128);
  k_transp<<<dim3(2, 2, 6), 256, 0, stream>>>(fcw, fcwt, 128, 128);
  k_transp<<<dim3(2, 40, 3), 256, 0, stream>>>(backw, backwt, 128, 2560);
  k_timegate<<<BN, 128, 0, stream>>>(hist, tod, emb, tg1w, tg1b, tg2w, tg2b,
                                     tg3w, tg3b, h_in, level, tgf, f_acc);
  k_dp<<<Nn, 256, 0, stream>>>(emb, dp);
  k_build_b<<<BN, 256, 0, stream>>>(h_in, level, dp, emb, xb);

  for (int i = 0; i < NBb; ++i) {
    const u16* W0t = fc0wt + (size_t)i*327680;
    const u16* W1t = fcwt + (size_t)(i*2+0)*16384;
    const u16* W2t = fcwt + (size_t)(i*2+1)*16384;
    const u16* BWt = backwt + (size_t)i*327680;
    if (i < NBb-1)
      k_mega<0><<<414, 512, 0, stream>>>(
          xb, W0t, fc0b + i*128, W1t, fcb + (i*2+0)*128, W2t, fcb + (i*2+1)*128,
          forew + (size_t)i*1536, foreb + i*12, BWt, backb + (size_t)i*2560,
          f_acc, nullptr);
    else
      k_mega<1><<<414, 512, 0, stream>>>(
          xb, W0t, fc0b + i*128, W1t, fcb + (i*2+0)*128, W2t, fcb + (i*2+1)*128,
          forew + (size_t)i*1536, foreb + i*12, BWt, backb + (size_t)i*2560,
          f_acc, x);
  }
  k_forecast<<<(BN*24 + 255)/256, 256, 0, stream>>>(f_acc, level, tgf, outf);
}

// Round 4
// 497.743 us; speedup vs baseline: 1.8068x; 1.8068x over previous
//
#include <hip/hip_runtime.h>
#include <math.h>

#define Bsz 32
#define Nn 207
#define Tt 12
#define Cc 2
#define HORr 12
#define DIDd 64
#define Hh 128
#define NBb 3
#define CONCATk 2560
#define BN (Bsz*Nn)           // 6624
#define ROWS (BN*Cc)          // 13248 = 414*32 = 207*64
#define XSTRIDE (CONCATk*Cc)  // 5120

typedef unsigned short u16;
typedef __attribute__((ext_vector_type(8))) short bf16x8;
typedef __attribute__((ext_vector_type(4))) float f32x4;

__device__ inline u16 f2b(float f) {
  unsigned u = __builtin_bit_cast(unsigned, f);
  u += 0x7fffu + ((u >> 16) & 1u);          // RNE
  return (u16)(u >> 16);
}
__device__ inline float b2f(u16 b) {
  unsigned u = ((unsigned)b) << 16;
  return __builtin_bit_cast(float, u);
}
__device__ inline void gld16(const void* g, void* l) {
  __builtin_amdgcn_global_load_lds((const __attribute__((address_space(1))) void*)g,
                                   (__attribute__((address_space(3))) void*)l, 16, 0, 0);
}

// ---------------- K1: time gates + h_in + level + zero f_acc ----------------
__global__ __launch_bounds__(128) void k_timegate(
    const float* __restrict__ hist, const float* __restrict__ tod,
    const float* __restrict__ emb,
    const float* __restrict__ w1, const float* __restrict__ b1,
    const float* __restrict__ w2, const float* __restrict__ b2,
    const float* __restrict__ w3, const float* __restrict__ b3,
    float* __restrict__ h_in, float* __restrict__ level,
    float* __restrict__ tgf, float* __restrict__ f_acc)
{
  int bn = blockIdx.x;
  int n = bn % Nn;
  __shared__ float s_in[76];
  __shared__ float s_tg[128];
  __shared__ float s_tgb[12];
  __shared__ float s_h[24];
  __shared__ float part[24][4];
  int tid = threadIdx.x;
  if (tid < 64) s_in[tid] = emb[n*64 + tid];
  else if (tid < 76) s_in[tid] = tod[bn*12 + (tid - 64)];
  __syncthreads();
  float acc = b1[tid];
#pragma unroll 4
  for (int k = 0; k < 76; ++k) acc = fmaf(s_in[k], w1[k*128 + tid], acc);
  s_tg[tid] = fmaxf(acc, 0.f);
  __syncthreads();
  // 24 outputs x 128-dot, split over 96 threads (4 partials each)
  if (tid < 96) {
    int j = tid >> 2, p = tid & 3;
    int jj = (j < 12) ? j : j - 12;
    const float* w = (j < 12) ? w2 : w3;
    float a = 0.f;
#pragma unroll 8
    for (int k = p*32; k < p*32 + 32; ++k) a = fmaf(s_tg[k], w[k*12 + jj], a);
    part[j][p] = a;
  }
  __syncthreads();
  if (tid < 24) {
    int jj = (tid < 12) ? tid : tid - 12;
    float a = ((tid < 12) ? b2[jj] : b3[jj])
            + part[tid][0] + part[tid][1] + part[tid][2] + part[tid][3];
    if (tid < 12) tgf[bn*12 + jj] = a;
    else s_tgb[jj] = a;
  }
  __syncthreads();
  if (tid < 24) {
    int t = tid >> 1;
    float v = hist[bn*24 + tid] / (1.f + s_tgb[t]);
    h_in[bn*24 + tid] = v;
    s_h[tid] = v;
    f_acc[bn*24 + tid] = 0.f;
  }
  __syncthreads();
  if (tid < 2) {
    float m = s_h[tid];
    for (int t = 1; t < 12; ++t) m = fmaxf(m, s_h[t*2 + tid]);
    level[bn*2 + tid] = m;
  }
}

// ---------------- K2: dp[n,m] = exp(10 * <emb_n, emb_m>) ----------------
__global__ __launch_bounds__(256) void k_dp(const float* __restrict__ emb,
                                            float* __restrict__ dp)
{
  int n = blockIdx.x;
  __shared__ float e[64];
  int tid = threadIdx.x;
  if (tid < 64) e[tid] = emb[n*64 + tid];
  __syncthreads();
  if (tid < Nn) {
    float a = 0.f;
#pragma unroll 8
    for (int k = 0; k < 64; ++k) a = fmaf(e[k], emb[tid*64 + k], a);
    dp[n*Nn + tid] = expf(10.f * a);
  }
}

// ---------------- weight transpose+convert: fp32 [K][N] -> bf16 [N][K] -------
__global__ __launch_bounds__(256) void k_transp(
    const float* __restrict__ src, u16* __restrict__ dst, int K, int N)
{
  int k0 = blockIdx.x*64, n0 = blockIdx.y*64;
  size_t mo = (size_t)blockIdx.z * K * N;
  src += mo; dst += mo;
  __shared__ u16 Ts[64][72];
  int tid = threadIdx.x;
#pragma unroll
  for (int it = 0; it < 4; ++it) {
    int idx = it*256 + tid;
    int r = idx >> 4, q = idx & 15;
    float4 v = *(const float4*)(src + (size_t)(k0 + r)*N + n0 + q*4);
    Ts[r][q*4+0] = f2b(v.x);
    Ts[r][q*4+1] = f2b(v.y);
    Ts[r][q*4+2] = f2b(v.z);
    Ts[r][q*4+3] = f2b(v.w);
  }
  __syncthreads();
#pragma unroll
  for (int it = 0; it < 2; ++it) {
    int idx = it*256 + tid;
    int nl = idx >> 3, kq = idx & 7;
    u16 o[8];
#pragma unroll
    for (int j = 0; j < 8; ++j) o[j] = Ts[kq*8 + j][nl];
    *(bf16x8*)(dst + (size_t)(n0 + nl)*K + k0 + kq*8) = *(bf16x8*)o;
  }
}

// ---------------- build xb bf16, row-major [r=bn*2+c][k] ---------------------
// Div-free rewrite: thread m (<207) computes all 12 t for both channels into
// an LDS row image; tail threads fill history/emb; then linear 16B stores.
__global__ __launch_bounds__(256) void k_build_b(
    const float* __restrict__ h_in, const float* __restrict__ level,
    const float* __restrict__ dp, const float* __restrict__ emb,
    u16* __restrict__ xb)
{
  int bn = blockIdx.x;
  int b = bn / Nn, n = bn - b*Nn;
  __shared__ float s_dp[Nn];
  __shared__ __attribute__((aligned(16))) u16 row[2][2560];
  int tid = threadIdx.x;
  for (int m = tid; m < Nn; m += 256) s_dp[m] = dp[n*Nn + m];
  float lev0 = level[bn*2], lev1 = level[bn*2+1];
  float inv0 = 1.f/(lev0+1e-8f), inv1 = 1.f/(lev1+1e-8f);
  __syncthreads();
  if (tid < Nn) {
    int m = tid;
    float dpm = s_dp[m];
    const float2* hp = (const float2*)(h_in + (size_t)(b*Nn + m)*24);
#pragma unroll
    for (int t = 0; t < 12; ++t) {
      float2 v = hp[t];
      row[0][12 + m*12 + t] = f2b(fmaxf((v.x*dpm - lev0)*inv0, 0.f));
      row[1][12 + m*12 + t] = f2b(fmaxf((v.y*dpm - lev1)*inv1, 0.f));
    }
  } else if (tid < 219) {            // history (12 t, both c)
    int t = tid - 207;
    float2 v = *(const float2*)(h_in + (size_t)bn*24 + t*2);
    row[0][t] = f2b(v.x*inv0);
    row[1][t] = f2b(v.y*inv1);
  } else if (tid < 251) {            // emb: 32 threads x 2 elems
    int e = (tid - 219)*2;
    float2 ev = *(const float2*)(emb + n*64 + e);
    u16 a = f2b(ev.x), bq = f2b(ev.y);
    row[0][2496+e] = a; row[0][2497+e] = bq;
    row[1][2496+e] = a; row[1][2497+e] = bq;
  }
  __syncthreads();
  for (int s = tid; s < 640; s += 256) {
    int c = s >= 320, ks = s - c*320;
    *(bf16x8*)(xb + (size_t)(bn*2 + c)*2560 + ks*8) = *(const bf16x8*)&row[c][ks*8];
  }
}

// ---------------- k_fc: fc0 -> h1 -> h2 -> h3 + fore; writes h3 --------------
// grid 414 (32-row tiles), 256 thr / 4 waves (wave tile 16x64), 51KB LDS ->
// 3 blocks/CU. fc0: 2-buf gld16 pipeline, one barrier + vmcnt(0) per K-step.
// Back phase removed (now k_back) -> per-block staged bytes 1.5MB -> 0.87MB,
// chain 68 -> 46 segments.
__global__ __launch_bounds__(256, 3) void k_fc(
    const u16* __restrict__ xb,
    const u16* __restrict__ W0t, const float* __restrict__ b0,
    const u16* __restrict__ W1t, const float* __restrict__ b1,
    const u16* __restrict__ W2t, const float* __restrict__ b2,
    const float* __restrict__ FW, const float* __restrict__ fb,
    float* __restrict__ f_acc, u16* __restrict__ h3)
{
  __shared__ __attribute__((aligned(16))) u16 As[2*2048];   //  8 KB A dbuf
  __shared__ __attribute__((aligned(16))) u16 Bs[2*8192];   // 32 KB B dbuf / W1,W2
  __shared__ __attribute__((aligned(16))) u16 Hs[4096];     //  8 KB h tile
  __shared__ __attribute__((aligned(16))) u16 sFw[1536];    //  3 KB FW bf16
  __shared__ float sFb[12];
  const int tid = threadIdx.x, wv = tid >> 6, lane = tid & 63;
  const int m16 = lane & 15, quad = lane >> 4;
  const int wr = (wv & 1) * 16, wc = (wv >> 1) * 64;
  const int r0 = blockIdx.x * 32;

  // fc0 staging maps (source pre-swizzled, LDS linear)
  const int s_row = tid >> 3, s_ch = tid & 7;
  const u16* a_src = xb + (size_t)(r0 + s_row)*2560 + (s_ch ^ (s_row & 7))*8;
  u16* a_dst = As + wv*512;
  const u16* b_src[4];
#pragma unroll
  for (int it = 0; it < 4; ++it) {
    int slot = it*256 + tid, nl = slot >> 3, g = (slot & 7) ^ (nl & 7);
    b_src[it] = W0t + (size_t)nl*2560 + g*8;
  }
  u16* b_dst = Bs + wv*512;
  auto issueF = [&](int t, int buf) {
    gld16(a_src + t*64, a_dst + buf*2048);
#pragma unroll
    for (int it = 0; it < 4; ++it)
      gld16(b_src[it] + t*64, b_dst + buf*8192 + it*2048);
  };

  issueF(0, 0);
  f32x4 acc[4] = {};
  for (int j = 0; j < 40; ++j) {
    const int buf = j & 1;
    asm volatile("s_waitcnt vmcnt(0)" ::: "memory");
    __builtin_amdgcn_sched_barrier(0);
    __builtin_amdgcn_s_barrier();
    __builtin_amdgcn_sched_barrier(0);
    if (j < 39) issueF(j + 1, buf ^ 1);
    const u16* Ab = As + buf*2048;
    const u16* Bb = Bs + buf*8192;
#pragma unroll
    for (int ks = 0; ks < 2; ++ks) {
      int cb = ks*4 + quad;
      int ar = wr + m16;
      bf16x8 a = *(const bf16x8*)&Ab[(ar*8 + (cb ^ (ar & 7)))*8];
#pragma unroll
      for (int jj = 0; jj < 4; ++jj) {
        int nl = wc + jj*16 + m16;
        bf16x8 b = *(const bf16x8*)&Bb[(nl*8 + (cb ^ (nl & 7)))*8];
        acc[jj] = __builtin_amdgcn_mfma_f32_16x16x32_bf16(a, b, acc[jj], 0, 0, 0);
      }
    }
  }

  // h-phase helpers (K=128, 16 granules, XOR-16 swizzle)
  auto stageW = [&](const u16* W) {
#pragma unroll
    for (int it = 0; it < 8; ++it) {
      int slot = it*256 + tid, nl = slot >> 4, g = (slot & 15) ^ (nl & 15);
      gld16(W + (size_t)nl*128 + g*8, Bs + it*2048 + wv*512);
    }
  };
  auto writeH = [&](const f32x4* ac, const float* bias) {
#pragma unroll
    for (int jj = 0; jj < 4; ++jj) {
      int col = wc + jj*16 + m16;
      float bv = bias[col];
#pragma unroll
      for (int reg = 0; reg < 4; ++reg) {
        int row = wr + quad*4 + reg;
        int chunk = col >> 3;
        Hs[(row*16 + (chunk ^ (row & 15)))*8 + (col & 7)] =
            f2b(fmaxf(ac[jj][reg] + bv, 0.f));
      }
    }
  };
  auto mm128 = [&](f32x4* ac) {
#pragma unroll
    for (int ks = 0; ks < 4; ++ks) {
      int cb = ks*4 + quad;
      int ar = wr + m16;
      bf16x8 a = *(const bf16x8*)&Hs[(ar*16 + (cb ^ (ar & 15)))*8];
#pragma unroll
      for (int jj = 0; jj < 4; ++jj) {
        int nl = wc + jj*16 + m16;
        bf16x8 b = *(const bf16x8*)&Bs[(nl*16 + (cb ^ (nl & 15)))*8];
        ac[jj] = __builtin_amdgcn_mfma_f32_16x16x32_bf16(a, b, ac[jj], 0, 0, 0);
      }
    }
  };

  __syncthreads();                 // fc0 LDS reads done everywhere
  stageW(W1t);
  for (int s = tid; s < 1536; s += 256) sFw[s] = f2b(FW[s]);
  if (tid < 12) sFb[tid] = fb[tid];
  writeH(acc, b0);                 // h1 -> Hs
  __syncthreads();

  f32x4 acc2[4] = {};
  mm128(acc2);
  __syncthreads();
  stageW(W2t);
  writeH(acc2, b1);                // h2 -> Hs
  __syncthreads();

  f32x4 acc3[4] = {};
  mm128(acc3);
  __syncthreads();
  writeH(acc3, b2);                // h3 -> Hs
  __syncthreads();

  // h3 store (linear global layout) + forecast accumulation
  for (int s = tid; s < 512; s += 256) {
    int row = s >> 4, g = s & 15;
    bf16x8 v = *(const bf16x8*)&Hs[(row*16 + (g ^ (row & 15)))*8];
    *(bf16x8*)(h3 + (size_t)(r0 + row)*128 + g*8) = v;
  }
  for (int o = tid; o < 384; o += 256) {
    int row = o / 12, t = o - (o/12)*12;
    float a = sFb[t];
#pragma unroll
    for (int chunk = 0; chunk < 16; ++chunk) {
      const u16* hp = &Hs[(row*16 + (chunk ^ (row & 15)))*8];
#pragma unroll
      for (int jq = 0; jq < 8; ++jq)
        a = fmaf(b2f(hp[jq]), b2f(sFw[(chunk*8 + jq)*12 + t]), a);
    }
    f_acc[(size_t)(r0 + row)*12 + t] += a;
  }
}

// ---------------- k_back: single-shot back GEMM tile + RMW epilogue ----------
// grid (207, 20): 64-row x 128-col output tiles, K=128 complete. 48KB LDS ->
// 3 blocks/CU; stage once, one barrier, 32 MFMA/wave, epilogue via LDS (Cs
// aliases staging) with coalesced 16B stores. FINAL=1 writes fp32 d_out.
template<int FINAL>
__global__ __launch_bounds__(256, 3) void k_back(
    const u16* __restrict__ h3, const u16* __restrict__ BWt,
    const float* __restrict__ bbias, u16* __restrict__ xb,
    float* __restrict__ xf)
{
  __shared__ __attribute__((aligned(16))) u16 Sm[24576];   // 48KB; aliased as Cs
  __shared__ float sBb[128];
  const int tid = threadIdx.x, wv = tid >> 6, lane = tid & 63;
  const int m16 = lane & 15, quad = lane >> 4;
  const int wr2 = (wv & 1) * 32, wc2 = (wv >> 1) * 64;
  const int gr0 = blockIdx.x * 64, n0 = blockIdx.y * 128;
  u16* Asl = Sm;             // h3 tile: 64 rows x 16 granules
  u16* Bsl = Sm + 8192;      // BW tile: 128 cols x 16 granules

#pragma unroll
  for (int it = 0; it < 4; ++it) {
    int slot = it*256 + tid, row = slot >> 4, g = (slot & 15) ^ (row & 15);
    gld16(h3 + (size_t)(gr0 + row)*128 + g*8, Asl + it*2048 + wv*512);
  }
#pragma unroll
  for (int it = 0; it < 8; ++it) {
    int slot = it*256 + tid, nl = slot >> 4, g = (slot & 15) ^ (nl & 15);
    gld16(BWt + (size_t)(n0 + nl)*128 + g*8, Bsl + it*2048 + wv*512);
  }
  if (tid < 128) sBb[tid] = bbias[n0 + tid];
  __syncthreads();

  f32x4 bacc[2][4] = {};
#pragma unroll
  for (int ks = 0; ks < 4; ++ks) {
    int cb = ks*4 + quad;
    int ar0 = wr2 + m16, ar1 = wr2 + 16 + m16;
    bf16x8 a0 = *(const bf16x8*)&Asl[(ar0*16 + (cb ^ (ar0 & 15)))*8];
    bf16x8 a1 = *(const bf16x8*)&Asl[(ar1*16 + (cb ^ (ar1 & 15)))*8];
#pragma unroll
    for (int jj = 0; jj < 4; ++jj) {
      int nl = wc2 + jj*16 + m16;
      bf16x8 b = *(const bf16x8*)&Bsl[(nl*16 + (cb ^ (nl & 15)))*8];
      bacc[0][jj] = __builtin_amdgcn_mfma_f32_16x16x32_bf16(a0, b, bacc[0][jj], 0, 0, 0);
      bacc[1][jj] = __builtin_amdgcn_mfma_f32_16x16x32_bf16(a1, b, bacc[1][jj], 0, 0, 0);
    }
  }
  __syncthreads();                 // staging reads done; alias Cs
  float* Cs = (float*)Sm;          // [64][132]
#pragma unroll
  for (int mi = 0; mi < 2; ++mi)
#pragma unroll
    for (int jj = 0; jj < 4; ++jj) {
      int col = wc2 + jj*16 + m16;
      float bb = sBb[col];
#pragma unroll
      for (int reg = 0; reg < 4; ++reg) {
        int row = wr2 + mi*16 + quad*4 + reg;
        Cs[row*132 + col] = bacc[mi][jj][reg] + bb;
      }
    }
  __syncthreads();
  if constexpr (!FINAL) {
    int row = tid >> 2, cq = tid & 3;
    u16* xp = xb + (size_t)(gr0 + row)*2560 + n0 + cq*32;
#pragma unroll
    for (int q = 0; q < 4; ++q) {
      bf16x8 old = *(const bf16x8*)(xp + q*8);
      u16 nv[8];
#pragma unroll
      for (int i = 0; i < 8; ++i)
        nv[i] = f2b(fmaxf(b2f((u16)old[i]) - Cs[row*132 + cq*32 + q*8 + i], 0.f));
      *(bf16x8*)(xp + q*8) = *(bf16x8*)nv;
    }
  } else {
    int p = tid >> 3, cg = tid & 7;
    int ra = 2*p, bn = (gr0 >> 1) + p;
    const u16* x0 = xb + (size_t)(gr0 + ra)*2560 + n0 + cg*16;
    const u16* x1 = x0 + 2560;
    float* op = xf + (size_t)bn*XSTRIDE + (size_t)(n0 + cg*16)*2;
#pragma unroll
    for (int q = 0; q < 2; ++q) {
      bf16x8 o0 = *(const bf16x8*)(x0 + q*8);
      bf16x8 o1 = *(const bf16x8*)(x1 + q*8);
#pragma unroll
      for (int i = 0; i < 8; i += 2) {
        int k = cg*16 + q*8 + i;
        float4 w;
        w.x = fmaxf(b2f((u16)o0[i])   - Cs[ra*132 + k],       0.f);
        w.y = fmaxf(b2f((u16)o1[i])   - Cs[(ra+1)*132 + k],   0.f);
        w.z = fmaxf(b2f((u16)o0[i+1]) - Cs[ra*132 + k + 1],   0.f);
        w.w = fmaxf(b2f((u16)o1[i+1]) - Cs[(ra+1)*132 + k + 1], 0.f);
        *(float4*)(op + (q*8 + i)*2) = w;
      }
    }
  }
}

// ---------------- finalize forecast ----------------
__global__ __launch_bounds__(256) void k_forecast(
    const float* __restrict__ f_acc, const float* __restrict__ level,
    const float* __restrict__ tgf, float* __restrict__ outf)
{
  int idx = blockIdx.x*256 + threadIdx.x;
  if (idx >= BN*24) return;
  int bn = idx / 24;
  int rem = idx - bn*24;
  int t = rem >> 1, c = rem & 1;
  float v = f_acc[bn*24 + c*12 + t];
  outf[idx] = v * level[bn*2 + c] * (1.f + tgf[bn*12 + t]);
}

extern "C" void kernel_launch(void* const* d_in, const int* in_sizes, int n_in,
                              void* d_out, int out_size, void* d_ws, size_t ws_size,
                              hipStream_t stream)
{
  const float* hist = (const float*)d_in[0];
  const float* tod  = (const float*)d_in[1];
  const float* emb  = (const float*)d_in[2];
  const float* tg1w = (const float*)d_in[3];
  const float* tg1b = (const float*)d_in[4];
  const float* tg2w = (const float*)d_in[5];
  const float* tg2b = (const float*)d_in[6];
  const float* tg3w = (const float*)d_in[7];
  const float* tg3b = (const float*)d_in[8];
  const float* fc0w = (const float*)d_in[9];
  const float* fc0b = (const float*)d_in[10];
  const float* fcw  = (const float*)d_in[11];
  const float* fcb  = (const float*)d_in[12];
  const float* forew= (const float*)d_in[13];
  const float* foreb= (const float*)d_in[14];
  const float* backw= (const float*)d_in[15];
  const float* backb= (const float*)d_in[16];

  char* w = (char*)d_ws;
  float* h_in  = (float*)w; w += 635904;     // 158976 f32
  float* level = (float*)w; w += 52992;      // 13248 f32
  float* tgf   = (float*)w; w += 317952;     // 79488 f32
  float* dp    = (float*)w; w += 171408;     // 42852 f32
  float* f_acc = (float*)w; w += 635904;     // 158976 f32
  u16* fc0wt   = (u16*)w;   w += 1966080;    // 3 x [128][2560]
  u16* fcwt    = (u16*)w;   w += 196608;     // 6 x [128][128]
  u16* backwt  = (u16*)w;   w += 1966080;    // 3 x [2560][128]
  u16* xb      = (u16*)w;   w += 67829760;   // 13248*2560 bf16
  u16* h3      = (u16*)w;   w += 3391488;    // 13248*128 bf16

  float* x    = (float*)d_out;                               // [bn][k][c] fp32
  float* outf = (float*)d_out + (size_t)BN*CONCATk*Cc;

  k_transp<<<dim3(40, 2, 3), 256, 0, stream>>>(fc0w, fc0wt, 2560, 128);
  k_transp<<<dim3(2, 2, 6), 256, 0, stream>>>(fcw, fcwt, 128, 128);
  k_transp<<<dim3(2, 40, 3), 256, 0, stream>>>(backw, backwt, 128, 2560);
  k_timegate<<<BN, 128, 0, stream>>>(hist, tod, emb, tg1w, tg1b, tg2w, tg2b,
                                     tg3w, tg3b, h_in, level, tgf, f_acc);
  k_dp<<<Nn, 256, 0, stream>>>(emb, dp);
  k_build_b<<<BN, 256, 0, stream>>>(h_in, level, dp, emb, xb);

  for (int i = 0; i < NBb; ++i) {
    const u16* W0t = fc0wt + (size_t)i*327680;
    const u16* W1t = fcwt + (size_t)(i*2+0)*16384;
    const u16* W2t = fcwt + (size_t)(i*2+1)*16384;
    const u16* BWt = backwt + (size_t)i*327680;
    k_fc<<<414, 256, 0, stream>>>(xb, W0t, fc0b + i*128, W1t, fcb + (i*2+0)*128,
                                  W2t, fcb + (i*2+1)*128, forew + (size_t)i*1536,
                                  foreb + i*12, f_acc, h3);
    if (i < NBb-1)
      k_back<0><<<dim3(207, 20), 256, 0, stream>>>(h3, BWt, backb + (size_t)i*2560,
                                                   xb, nullptr);
    else
      k_back<1><<<dim3(207, 20), 256, 0, stream>>>(h3, BWt, backb + (size_t)i*2560,
                                                   xb, x);
  }
  k_forecast<<<(BN*24 + 255)/256, 256, 0, stream>>>(f_acc, level, tgf, outf);
}